// Round 1
// baseline (52.026 us; speedup 1.0000x reference)
//
#include <hip/hip_runtime.h>
#include <math.h>

// Problem constants (fixed by setup_inputs)
constexpr int B_  = 8;
constexpr int C_  = 64;
constexpr int H_  = 112;
constexpr int W_  = 112;
constexpr int KH  = 5;
constexpr int KW  = 5;
constexpr int PAD = 2;

constexpr int TR  = 16;            // output rows per tile
constexpr int LR  = TR + KH - 1;   // 20 LDS rows
constexpr int LC  = W_ + KW - 1;   // 116 LDS cols
constexpr int TPB = 256;
constexpr int OPT = 7;             // outputs per thread along W (16 col-groups * 7 = 112)
constexpr int TILES = H_ / TR;     // 7

// Soft-morphology (func_type==1) via factored softmax:
//   y_k = x_k + w_k ;  e^{a y_k} = e^{a x_k} * e^{a w_k}
//   E = e^{a x}, F = x E (per input pixel, ONCE)
//   u_k = e^{a w_k}, v_k = w_k u_k (per channel)
//   out = s * ( (corr(F,u) + corr(E,v)) / corr(E,u) + bias )
// Zero-padded taps => E=1, F=0.
__global__ __launch_bounds__(TPB)
void morpho_softmax_kernel(const float* __restrict__ x,
                           const float* __restrict__ weight,
                           const float* __restrict__ bias,
                           const float* __restrict__ sign,
                           const int*   __restrict__ alpha_p,
                           float* __restrict__ out)
{
    __shared__ float sE[LR][LC];
    __shared__ float sF[LR][LC];
    __shared__ float sU[KH * KW];
    __shared__ float sV[KH * KW];

    const int tile  = blockIdx.x;          // 0..TILES-1
    const int plane = blockIdx.y;          // 0..B*C-1  (b = plane/C, c = plane%C)
    const int c     = plane & (C_ - 1);
    const int tid   = threadIdx.x;

    const float sg    = sign[0];
    const float seff  = (fabsf(sg) >= 1e-7f) ? sg : 1.0f;
    const float alpha = (float)alpha_p[0];

    // per-channel weight transforms (25 exps per block, broadcast via LDS)
    if (tid < KH * KW) {
        float w = weight[c * (KH * KW) + tid];
        float u = __expf(alpha * w);
        sU[tid] = u;
        sV[tid] = w * u;
    }

    const float* xp   = x + (size_t)plane * (H_ * W_);
    const int    row0 = tile * TR - PAD;

    // stage E, F tile (+halo) into LDS; out-of-image => E=1, F=0
    for (int idx = tid; idx < LR * LC; idx += TPB) {
        int r   = idx / LC;
        int col = idx - r * LC;
        int gr  = row0 + r;
        int gc  = col - PAD;
        float e = 1.0f, f = 0.0f;
        if (gr >= 0 && gr < H_ && gc >= 0 && gc < W_) {
            float v = seff * xp[gr * W_ + gc];
            e = __expf(alpha * v);
            f = v * e;
        }
        sE[r][col] = e;
        sF[r][col] = f;
    }
    __syncthreads();

    const int ty = tid >> 4;     // 0..15 : output row within tile
    const int tx = tid & 15;     // 0..15 : col group
    const int c0 = tx * OPT;     // starting output col

    float Z[OPT], Nm[OPT];
#pragma unroll
    for (int o = 0; o < OPT; ++o) { Z[o] = 0.0f; Nm[o] = 0.0f; }

#pragma unroll
    for (int r = 0; r < KH; ++r) {
        float e[OPT + KW - 1], f[OPT + KW - 1];
#pragma unroll
        for (int j = 0; j < OPT + KW - 1; ++j) {
            e[j] = sE[ty + r][c0 + j];
            f[j] = sF[ty + r][c0 + j];
        }
#pragma unroll
        for (int j = 0; j < KW; ++j) {
            float u = sU[r * KW + j];
            float v = sV[r * KW + j];
#pragma unroll
            for (int o = 0; o < OPT; ++o) {
                Z[o]  = fmaf(u, e[o + j], Z[o]);
                Nm[o] = fmaf(u, f[o + j], fmaf(v, e[o + j], Nm[o]));
            }
        }
    }

    const float bc = bias[c];
    float* op = out + (size_t)plane * (H_ * W_) + (size_t)(tile * TR + ty) * W_ + c0;
#pragma unroll
    for (int o = 0; o < OPT; ++o) {
        op[o] = seff * (Nm[o] / Z[o] + bc);
    }
}

extern "C" void kernel_launch(void* const* d_in, const int* in_sizes, int n_in,
                              void* d_out, int out_size, void* d_ws, size_t ws_size,
                              hipStream_t stream) {
    // setup_inputs order: x, weight, bias, sign, padding, stride, func_type, alpha
    const float* x      = (const float*)d_in[0];
    const float* weight = (const float*)d_in[1];
    const float* bias   = (const float*)d_in[2];
    const float* sign   = (const float*)d_in[3];
    const int*   alpha  = (const int*)d_in[7];
    float* out = (float*)d_out;

    dim3 grid(TILES, B_ * C_);
    dim3 block(TPB);
    morpho_softmax_kernel<<<grid, block, 0, stream>>>(x, weight, bias, sign, alpha, out);
}

// Round 4
// 33.245 us; speedup vs baseline: 1.5649x; 1.5649x over previous
//
#include <hip/hip_runtime.h>
#include <math.h>

// Problem constants (fixed by setup_inputs)
constexpr int B_  = 8;
constexpr int C_  = 64;
constexpr int H_  = 112;
constexpr int W_  = 112;
constexpr int KH  = 5;
constexpr int KW  = 5;
constexpr int PAD = 2;

constexpr int TR   = 16;            // output rows per tile
constexpr int LR   = TR + KH - 1;   // 20 staged rows
constexpr int LCP  = 117;           // padded float2 row stride (116 cols + 1 pad)
constexpr int TPB  = 128;
constexpr int TILES = H_ / TR;      // 7
constexpr int SOUT_LD = 116;        // output restage stride (mult of 4 for float4)

// ---------------------------------------------------------------------------
// prep: per-channel weight transforms  u_k = e^{alpha*w_k},  v_k = w_k*u_k
// layout in ws: uv[c*50 + k] = u_k, uv[c*50 + 25 + k] = v_k
// ---------------------------------------------------------------------------
__global__ void prep_uv(const float* __restrict__ w,
                        const int* __restrict__ alpha_p,
                        float* __restrict__ uv)
{
    int i = blockIdx.x * blockDim.x + threadIdx.x;
    if (i >= C_ * KH * KW) return;
    int c = i / 25, k = i - 25 * c;
    float a  = (float)alpha_p[0];
    float wv = w[i];
    float u  = __expf(a * wv);
    uv[c * 50 + k]      = u;
    uv[c * 50 + 25 + k] = wv * u;
}

// ---------------------------------------------------------------------------
// main: soft-morphology via factored softmax
//   E = e^{a*s*x}, F = (s*x)*E  (once per input pixel, staged in LDS as float2)
//   out = s * ( (corr(F,u) + corr(E,v)) / corr(E,u) + bias )
// Zero-padded taps => E=1, F=0.
// ---------------------------------------------------------------------------
__global__ __launch_bounds__(TPB)
void morpho_main(const float* __restrict__ x,
                 const float* __restrict__ uv,
                 const float* __restrict__ bias,
                 const float* __restrict__ sign,
                 const int*   __restrict__ alpha_p,
                 float* __restrict__ out)
{
    // union of EF tile (20*117 float2 = 18720 B) and output restage (16*116 f32)
    __shared__ __align__(16) char smraw[LR * LCP * sizeof(float2)];
    float2 (*sEF)[LCP] = reinterpret_cast<float2 (*)[LCP]>(smraw);

    const int tile  = blockIdx.x;         // 0..6
    const int plane = blockIdx.y;         // 0..511 (b*C + c)
    const int c     = plane & (C_ - 1);
    const int tid   = threadIdx.x;

    const float sg   = sign[0];
    const float seff = (fabsf(sg) >= 1e-7f) ? sg : 1.0f;
    const float aK   = (float)alpha_p[0] * seff;   // exp(aK * raw_x)

    const float* xp  = x + (size_t)plane * (H_ * W_);
    const int   row0 = tile * TR - PAD;

    // ---- halo columns (image cols -2,-1,112,113 => E=1, F=0) ----
    for (int i = tid; i < LR * 4; i += TPB) {
        int r = i >> 2, q = i & 3;
        int col = (q < 2) ? q : (W_ + q);          // 0,1,114,115
        sEF[r][col] = make_float2(1.0f, 0.0f);
    }
    // ---- interior: 20 rows x 28 float4 (rows are 448B-aligned) ----
    for (int i = tid; i < LR * 28; i += TPB) {
        int r  = i / 28;
        int q  = i - 28 * r;
        int gr = row0 + r;
        float e0, e1, e2, e3, f0, f1, f2, f3;
        if (gr >= 0 && gr < H_) {
            const float4 xv = *reinterpret_cast<const float4*>(xp + gr * W_ + 4 * q);
            e0 = __expf(aK * xv.x); f0 = (seff * xv.x) * e0;
            e1 = __expf(aK * xv.y); f1 = (seff * xv.y) * e1;
            e2 = __expf(aK * xv.z); f2 = (seff * xv.z) * e2;
            e3 = __expf(aK * xv.w); f3 = (seff * xv.w) * e3;
        } else {
            e0 = e1 = e2 = e3 = 1.0f;
            f0 = f1 = f2 = f3 = 0.0f;
        }
        float4* dst = reinterpret_cast<float4*>(&sEF[r][2 + 4 * q]);
        dst[0] = make_float4(e0, f0, e1, f1);
        dst[1] = make_float4(e2, f2, e3, f3);
    }
    __syncthreads();

    // ---- compute: 2x7 output patch per thread ----
    const int ty = tid >> 4;      // 0..7 -> output rows 2ty, 2ty+1
    const int tx = tid & 15;      // 0..15 -> cols [7tx, 7tx+7)
    const int c0 = tx * 7;
    const float* uvp = uv + c * 50;   // workgroup-uniform -> s_load

    float Zr[2][7], Nr[2][7];
#pragma unroll
    for (int orow = 0; orow < 2; ++orow)
#pragma unroll
        for (int o = 0; o < 7; ++o) { Zr[orow][o] = 0.0f; Nr[orow][o] = 0.0f; }

#pragma unroll
    for (int rr = 0; rr < 6; ++rr) {   // 6 staged rows feed this thread's 2 output rows
        float2 ew[11];
#pragma unroll
        for (int jj = 0; jj < 11; ++jj) ew[jj] = sEF[2 * ty + rr][c0 + jj];
#pragma unroll
        for (int orow = 0; orow < 2; ++orow) {
            const int kr = rr - orow;
            if (kr < 0 || kr >= KH) continue;       // compile-time resolved
#pragma unroll
            for (int j = 0; j < KW; ++j) {
                const float u = uvp[kr * 5 + j];
                const float v = uvp[25 + kr * 5 + j];
#pragma unroll
                for (int o = 0; o < 7; ++o) {
                    const float E = ew[o + j].x;
                    const float F = ew[o + j].y;
                    Zr[orow][o] = fmaf(u, E, Zr[orow][o]);
                    Nr[orow][o] = fmaf(u, F, fmaf(v, E, Nr[orow][o]));
                }
            }
        }
    }

    // ---- epilogue: rcp + restage to LDS for coalesced float4 stores ----
    __syncthreads();   // all sEF reads done before aliasing as sOut
    float* sOut = reinterpret_cast<float*>(smraw);
    const float bc = bias[c];
#pragma unroll
    for (int orow = 0; orow < 2; ++orow)
#pragma unroll
        for (int o = 0; o < 7; ++o) {
            float val = seff * (Nr[orow][o] * __builtin_amdgcn_rcpf(Zr[orow][o]) + bc);
            sOut[(2 * ty + orow) * SOUT_LD + c0 + o] = val;
        }
    __syncthreads();

    float* op = out + (size_t)plane * (H_ * W_) + (size_t)(tile * TR) * W_;
    for (int i = tid; i < TR * 28; i += TPB) {
        int r = i / 28;
        int q = i - 28 * r;
        float4 vv = *reinterpret_cast<const float4*>(&sOut[r * SOUT_LD + 4 * q]);
        *reinterpret_cast<float4*>(op + r * W_ + 4 * q) = vv;
    }
}

extern "C" void kernel_launch(void* const* d_in, const int* in_sizes, int n_in,
                              void* d_out, int out_size, void* d_ws, size_t ws_size,
                              hipStream_t stream) {
    // setup_inputs order: x, weight, bias, sign, padding, stride, func_type, alpha
    const float* x      = (const float*)d_in[0];
    const float* weight = (const float*)d_in[1];
    const float* bias   = (const float*)d_in[2];
    const float* sign   = (const float*)d_in[3];
    const int*   alpha  = (const int*)d_in[7];
    float* out = (float*)d_out;
    float* uv  = (float*)d_ws;    // 64*50*4 = 12.8 KB of scratch

    prep_uv<<<(C_ * KH * KW + 255) / 256, 256, 0, stream>>>(weight, alpha, uv);

    dim3 grid(TILES, B_ * C_);
    morpho_main<<<grid, TPB, 0, stream>>>(x, uv, bias, sign, alpha, out);
}

// Round 5
// 32.394 us; speedup vs baseline: 1.6060x; 1.0263x over previous
//
#include <hip/hip_runtime.h>
#include <math.h>

// Problem constants (fixed by setup_inputs)
constexpr int B_  = 8;
constexpr int C_  = 64;
constexpr int H_  = 112;
constexpr int W_  = 112;
constexpr int KH  = 5;
constexpr int KW  = 5;
constexpr int PAD = 2;

constexpr int TRR  = 8;             // output rows per tile
constexpr int LR   = TRR + KH - 1;  // 12 staged rows
constexpr int LCP  = 117;           // float2 per row: 2 halo + 112 + 2 halo + 1 pad
constexpr int TPB  = 128;
constexpr int NTILES = H_ / TRR;    // 14
constexpr int SOUT_LD = 116;        // f32 restage stride (mult of 4)
constexpr int NINT = LR * 28;       // 336 interior float4 staging items

// ---------------------------------------------------------------------------
// prep: per-channel weight transforms  u_k = e^{alpha*w_k},  v_k = w_k*u_k
// layout in ws: uv[c*50 + k] = u_k, uv[c*50 + 25 + k] = v_k
// ---------------------------------------------------------------------------
__global__ void prep_uv(const float* __restrict__ w,
                        const int* __restrict__ alpha_p,
                        float* __restrict__ uv)
{
    int i = blockIdx.x * blockDim.x + threadIdx.x;
    if (i >= C_ * KH * KW) return;
    int c = i / 25, k = i - 25 * c;
    float a  = (float)alpha_p[0];
    float wv = w[i];
    float u  = __expf(a * wv);
    uv[c * 50 + k]      = u;
    uv[c * 50 + 25 + k] = wv * u;
}

// ---------------------------------------------------------------------------
// main: soft-morphology via factored softmax
//   E = e^{a*s*x}, F = (s*x)*E  (once per input pixel, staged in LDS as float2)
//   out = s*( (corr(F,u)+corr(E,v)) / corr(E,u) ) + s*bias
// Zero-padded taps => E=1, F=0.
// 8-row tile, LDS 11232 B -> ~12-14 blocks/CU for 6-7 waves/SIMD.
// ---------------------------------------------------------------------------
__global__ __launch_bounds__(TPB, 6)
void morpho_main(const float* __restrict__ x,
                 const float* __restrict__ uv,
                 const float* __restrict__ bias,
                 const float* __restrict__ sign,
                 const int*   __restrict__ alpha_p,
                 float* __restrict__ out)
{
    // union of EF tile (12*117 float2 = 11232 B) and output restage (8*116 f32)
    __shared__ __align__(16) char smraw[LR * LCP * sizeof(float2)];
    float2 (*sEF)[LCP] = reinterpret_cast<float2 (*)[LCP]>(smraw);

    const int tile  = blockIdx.x;         // 0..13
    const int plane = blockIdx.y;         // 0..511 (b*C + c)
    const int c     = plane & (C_ - 1);
    const int tid   = threadIdx.x;

    const float sg   = sign[0];
    const float seff = (fabsf(sg) >= 1e-7f) ? sg : 1.0f;
    const float aK   = (float)alpha_p[0] * seff;   // E = exp(aK * raw_x)

    const float* xp  = x + (size_t)plane * (H_ * W_);
    const int   row0 = tile * TRR - PAD;

    // ---- staging: hoist ALL global loads, then transform, then ds_write ----
    float4 xv[3];
    int    rr_[3], qq_[3];
    bool   rowok[3], itemok[3];
#pragma unroll
    for (int k = 0; k < 3; ++k) {
        int i  = tid + TPB * k;           // 0..383
        int ic = (i < NINT) ? i : (NINT - 1);
        int r  = ic / 28;                 // magic-mul
        int q  = ic - r * 28;
        int gr = row0 + r;
        int grc = min(max(gr, 0), H_ - 1);    // clamped -> load always in-bounds
        xv[k] = *reinterpret_cast<const float4*>(xp + grc * W_ + 4 * q);
        rr_[k] = r; qq_[k] = q;
        rowok[k]  = (gr >= 0) && (gr < H_);
        itemok[k] = (i < NINT);
    }
#pragma unroll
    for (int k = 0; k < 3; ++k) {
        if (itemok[k]) {
            float4 v = xv[k];
            bool ok = rowok[k];
            float e0 = ok ? __expf(aK * v.x) : 1.0f;
            float e1 = ok ? __expf(aK * v.y) : 1.0f;
            float e2 = ok ? __expf(aK * v.z) : 1.0f;
            float e3 = ok ? __expf(aK * v.w) : 1.0f;
            float f0 = ok ? (seff * v.x) * e0 : 0.0f;
            float f1 = ok ? (seff * v.y) * e1 : 0.0f;
            float f2 = ok ? (seff * v.z) * e2 : 0.0f;
            float f3 = ok ? (seff * v.w) * e3 : 0.0f;
            float4* dst = reinterpret_cast<float4*>(&sEF[rr_[k]][2 + 4 * qq_[k]]);
            dst[0] = make_float4(e0, f0, e1, f1);
            dst[1] = make_float4(e2, f2, e3, f3);
        }
    }
    // halo columns (image cols -2,-1,112,113 => E=1, F=0): 12 rows x 2 sides
    if (tid >= 104) {                     // 24 threads
        int t = tid - 104;
        int r = t >> 1;
        int fi = (t & 1) ? 114 : 0;       // float2 index, both 16B-aligned
        *reinterpret_cast<float4*>(&sEF[r][fi]) = make_float4(1.0f, 0.0f, 1.0f, 0.0f);
    }
    __syncthreads();

    // ---- compute: 1x7 outputs per thread ----
    const int ty = tid >> 4;      // 0..7 : output row within tile
    const int tx = tid & 15;      // 0..15: col group
    const int c0 = tx * 7;
    const float* uvp = uv + c * 50;   // workgroup-uniform -> s_load

    float Z[7], Nm[7];
#pragma unroll
    for (int o = 0; o < 7; ++o) { Z[o] = 0.0f; Nm[o] = 0.0f; }

#pragma unroll
    for (int rr = 0; rr < KH; ++rr) {
        float2 ew[11];
#pragma unroll
        for (int jj = 0; jj < 11; ++jj) ew[jj] = sEF[ty + rr][c0 + jj];
#pragma unroll
        for (int j = 0; j < KW; ++j) {
            const float u = uvp[rr * 5 + j];
            const float v = uvp[25 + rr * 5 + j];
#pragma unroll
            for (int o = 0; o < 7; ++o) {
                const float E = ew[o + j].x;
                const float F = ew[o + j].y;
                Z[o]  = fmaf(u, E, Z[o]);
                Nm[o] = fmaf(u, F, fmaf(v, E, Nm[o]));
            }
        }
    }

    // ---- epilogue: rcp + restage to LDS for coalesced float4 stores ----
    __syncthreads();   // all sEF reads done before aliasing as sOut
    float* sOut = reinterpret_cast<float*>(smraw);
    const float sb = seff * bias[c];
#pragma unroll
    for (int o = 0; o < 7; ++o) {
        float val = fmaf(seff * Nm[o], __builtin_amdgcn_rcpf(Z[o]), sb);
        sOut[ty * SOUT_LD + c0 + o] = val;
    }
    __syncthreads();

    float* op = out + (size_t)plane * (H_ * W_) + (size_t)(tile * TRR) * W_;
#pragma unroll
    for (int k = 0; k < 2; ++k) {
        int i = tid + TPB * k;
        if (i < TRR * 28) {               // 224 float4 stores
            int r = i / 28;
            int q = i - 28 * r;
            *reinterpret_cast<float4*>(op + r * W_ + 4 * q) =
                *reinterpret_cast<const float4*>(&sOut[r * SOUT_LD + 4 * q]);
        }
    }
}

extern "C" void kernel_launch(void* const* d_in, const int* in_sizes, int n_in,
                              void* d_out, int out_size, void* d_ws, size_t ws_size,
                              hipStream_t stream) {
    // setup_inputs order: x, weight, bias, sign, padding, stride, func_type, alpha
    const float* x      = (const float*)d_in[0];
    const float* weight = (const float*)d_in[1];
    const float* bias   = (const float*)d_in[2];
    const float* sign   = (const float*)d_in[3];
    const int*   alpha  = (const int*)d_in[7];
    float* out = (float*)d_out;
    float* uv  = (float*)d_ws;    // 64*50*4 = 12.8 KB of scratch

    prep_uv<<<(C_ * KH * KW + 255) / 256, 256, 0, stream>>>(weight, alpha, uv);

    dim3 grid(NTILES, B_ * C_);
    morpho_main<<<grid, TPB, 0, stream>>>(x, uv, bias, sign, alpha, out);
}

// Round 8
// 29.422 us; speedup vs baseline: 1.7683x; 1.1010x over previous
//
#include <hip/hip_runtime.h>
#include <math.h>

// Problem constants (fixed by setup_inputs)
constexpr int B_  = 8;
constexpr int C_  = 64;
constexpr int H_  = 112;
constexpr int W_  = 112;
constexpr int KH  = 5;
constexpr int KW  = 5;
constexpr int PAD = 2;

constexpr int TRR  = 8;             // output rows per tile
constexpr int LR   = TRR + KH - 1;  // 12 staged rows
constexpr int LCP  = 118;           // float2 row stride: even -> every row 16B-aligned
constexpr int TPB  = 128;
constexpr int NTILES = H_ / TRR;    // 14
constexpr int SOUT_LD = 116;        // f32 restage stride (mult of 4)
constexpr int NINT = LR * 28;       // 336 interior float4 staging items

// ---------------------------------------------------------------------------
// Fused soft-morphology (func_type==1) via factored softmax:
//   E = e^{a*s*x}, F = (s*x)*E   staged once per input pixel in LDS (float2)
//   u_k = e^{a*w_k}, v_k = w_k*u_k  computed per-thread into REGISTERS
//   out = s*( (corr(F,u)+corr(E,v)) * rcp(corr(E,u)) ) + s*bias
// Zero-padded taps => E=1, F=0.  Inner loop: pure FMA + ds_read, no loads.
// ---------------------------------------------------------------------------
__global__ __launch_bounds__(TPB, 4)
void morpho_fused(const float* __restrict__ x,
                  const float* __restrict__ weight,
                  const float* __restrict__ bias,
                  const float* __restrict__ sign,
                  const int*   __restrict__ alpha_p,
                  float* __restrict__ out)
{
    // union of EF tile (12*118 float2 = 11328 B) and output restage (8*116 f32)
    __shared__ __align__(16) char smraw[LR * LCP * sizeof(float2)];
    float2 (*sEF)[LCP] = reinterpret_cast<float2 (*)[LCP]>(smraw);

    const int tile  = blockIdx.x;         // 0..13
    const int plane = blockIdx.y;         // 0..511 (b*C + c)
    const int c     = plane & (C_ - 1);
    const int tid   = threadIdx.x;

    const float sg   = sign[0];
    const float seff = (fabsf(sg) >= 1e-7f) ? sg : 1.0f;
    const float a    = (float)alpha_p[0];
    const float aK   = a * seff;          // E = exp(aK * raw_x)

    const float* xp  = x + (size_t)plane * (H_ * W_);
    const int   row0 = tile * TRR - PAD;

    // ---- issue ALL staging global loads first (latency overlaps uv work) ----
    float4 xv[3];
    int    rr_[3], qq_[3];
    bool   rowok[3], itemok[3];
#pragma unroll
    for (int k = 0; k < 3; ++k) {
        int i  = tid + TPB * k;           // 0..383
        int ic = (i < NINT) ? i : (NINT - 1);
        int r  = ic / 28;
        int q  = ic - r * 28;
        int gr = row0 + r;
        int grc = min(max(gr, 0), H_ - 1);    // clamp -> always in-bounds
        xv[k] = *reinterpret_cast<const float4*>(xp + grc * W_ + 4 * q);
        rr_[k] = r; qq_[k] = q;
        rowok[k]  = (gr >= 0) && (gr < H_);
        itemok[k] = (i < NINT);
    }

    // ---- per-thread weight transforms into registers (uniform s_loads) ----
    const float* wp = weight + c * (KH * KW);
    float su[KH * KW], sv[KH * KW];
#pragma unroll
    for (int k = 0; k < KH * KW; ++k) {
        float wv = wp[k];
        float u  = __expf(a * wv);
        su[k] = u;
        sv[k] = wv * u;
    }

    // ---- transform staged pixels and write LDS ----
#pragma unroll
    for (int k = 0; k < 3; ++k) {
        if (itemok[k]) {
            float4 v = xv[k];
            bool ok = rowok[k];
            float e0 = ok ? __expf(aK * v.x) : 1.0f;
            float e1 = ok ? __expf(aK * v.y) : 1.0f;
            float e2 = ok ? __expf(aK * v.z) : 1.0f;
            float e3 = ok ? __expf(aK * v.w) : 1.0f;
            float f0 = ok ? (seff * v.x) * e0 : 0.0f;
            float f1 = ok ? (seff * v.y) * e1 : 0.0f;
            float f2 = ok ? (seff * v.z) * e2 : 0.0f;
            float f3 = ok ? (seff * v.w) * e3 : 0.0f;
            float4* dst = reinterpret_cast<float4*>(&sEF[rr_[k]][2 + 4 * qq_[k]]);
            dst[0] = make_float4(e0, f0, e1, f1);
            dst[1] = make_float4(e2, f2, e3, f3);
        }
    }
    // halo columns (image cols -2,-1,112,113 => E=1, F=0): 12 rows x 2 sides
    if (tid >= 104) {                     // 24 threads
        int t = tid - 104;
        int r = t >> 1;
        int fi = (t & 1) ? 114 : 0;       // float2 col; byte off 944r+{0,912}: 16B-aligned
        *reinterpret_cast<float4*>(&sEF[r][fi]) = make_float4(1.0f, 0.0f, 1.0f, 0.0f);
    }
    __syncthreads();

    // ---- compute: 1x7 outputs per thread; pure FMA + ds_read ----
    const int ty = tid >> 4;      // 0..7 : output row within tile
    const int tx = tid & 15;      // 0..15: col group
    const int c0 = tx * 7;

    float Z[7], Nm[7];
#pragma unroll
    for (int o = 0; o < 7; ++o) { Z[o] = 0.0f; Nm[o] = 0.0f; }

#pragma unroll
    for (int rr = 0; rr < KH; ++rr) {
        float2 ew[11];
#pragma unroll
        for (int jj = 0; jj < 11; ++jj) ew[jj] = sEF[ty + rr][c0 + jj];
#pragma unroll
        for (int j = 0; j < KW; ++j) {
            const float u = su[rr * 5 + j];
            const float v = sv[rr * 5 + j];
#pragma unroll
            for (int o = 0; o < 7; ++o) {
                const float E = ew[o + j].x;
                const float F = ew[o + j].y;
                Z[o]  = fmaf(u, E, Z[o]);
                Nm[o] = fmaf(u, F, fmaf(v, E, Nm[o]));
            }
        }
    }

    // ---- epilogue: rcp + restage to LDS for coalesced float4 stores ----
    __syncthreads();   // all sEF reads done before aliasing as sOut
    float* sOut = reinterpret_cast<float*>(smraw);
    const float sb = seff * bias[c];
#pragma unroll
    for (int o = 0; o < 7; ++o) {
        float val = fmaf(seff * Nm[o], __builtin_amdgcn_rcpf(Z[o]), sb);
        sOut[ty * SOUT_LD + c0 + o] = val;
    }
    __syncthreads();

    float* op = out + (size_t)plane * (H_ * W_) + (size_t)(tile * TRR) * W_;
#pragma unroll
    for (int k = 0; k < 2; ++k) {
        int i = tid + TPB * k;
        if (i < TRR * 28) {               // 224 float4 stores
            int r = i / 28;
            int q = i - 28 * r;
            *reinterpret_cast<float4*>(op + r * W_ + 4 * q) =
                *reinterpret_cast<const float4*>(&sOut[r * SOUT_LD + 4 * q]);
        }
    }
}

extern "C" void kernel_launch(void* const* d_in, const int* in_sizes, int n_in,
                              void* d_out, int out_size, void* d_ws, size_t ws_size,
                              hipStream_t stream) {
    // setup_inputs order: x, weight, bias, sign, padding, stride, func_type, alpha
    const float* x      = (const float*)d_in[0];
    const float* weight = (const float*)d_in[1];
    const float* bias   = (const float*)d_in[2];
    const float* sign   = (const float*)d_in[3];
    const int*   alpha  = (const int*)d_in[7];
    float* out = (float*)d_out;

    dim3 grid(NTILES, B_ * C_);
    morpho_fused<<<grid, TPB, 0, stream>>>(x, weight, bias, sign, alpha, out);
}